// Round 9
// baseline (146.764 us; speedup 1.0000x reference)
//
#include <hip/hip_runtime.h>
#include <hip/hip_bf16.h>
#include <cstdint>
#include <cstddef>

// Problem constants
#define BATCH 8
#define SEQ   2048
#define DIN   1024
// Fused QKV gemm N = 192 (Q:0-63, K:64-127, V:128-191) -> 12 n-tiles of 16

typedef float f32x4 __attribute__((ext_vector_type(4)));
typedef float f32x8 __attribute__((ext_vector_type(8)));
typedef __bf16 bf16x8 __attribute__((ext_vector_type(8)));
typedef unsigned short ushort8_t __attribute__((ext_vector_type(8)));

__device__ __forceinline__ unsigned short bfu(float f) {
  __bf16 h = (__bf16)f;            // HW v_cvt, RNE
  return __builtin_bit_cast(unsigned short, h);
}

__device__ __forceinline__ bf16x8 cvt8pair(float4 a, float4 b) {
  f32x8 v;
  v[0] = a.x; v[1] = a.y; v[2] = a.z; v[3] = a.w;
  v[4] = b.x; v[5] = b.y; v[6] = b.z; v[7] = b.w;
  return __builtin_convertvector(v, bf16x8);
}

// ---------------------------------------------------------------------------
// Kernel 0: pack Wq|Wk|Wv (fp32 [1024,64] each) into bf16 MFMA B-fragment
// order. Wp[nt*2048 + ks*64 + lane][j] =
//   W[k = ks*32 + (lane>>4)*8 + j][n = nt*16 + (lane&15)]
// Wq gets the 1/sqrt(64) = 0.125 softmax scale folded in.
// ---------------------------------------------------------------------------
__global__ void pack_w(const float* __restrict__ Wq, const float* __restrict__ Wk,
                       const float* __restrict__ Wv, unsigned short* __restrict__ Wp) {
  const int t = blockIdx.x * blockDim.x + threadIdx.x;   // 0..24575
  const int lane = t & 63;
  const int grp = t >> 6;       // 0..383
  const int ks = grp & 31;      // k-step
  const int nt = grp >> 5;      // n-tile 0..11
  const int n = nt * 16 + (lane & 15);
  const int k0 = ks * 32 + ((lane >> 4) << 3);
  const float* W;
  int col;
  float scale = 1.0f;
  if (n < 64)       { W = Wq; col = n;       scale = 0.125f; }
  else if (n < 128) { W = Wk; col = n - 64;  }
  else              { W = Wv; col = n - 128; }
  ushort8_t out;
#pragma unroll
  for (int j = 0; j < 8; ++j)
    out[j] = bfu(W[(size_t)(k0 + j) * 64 + col] * scale);
  reinterpret_cast<ushort8_t*>(Wp)[t] = out;
}

// ---------------------------------------------------------------------------
// Kernel 1: fused QKV projection. M=16384, K=1024, N=192.
// Block = 32 rows, grid 512 (2 blocks/CU). Two half-phases: stage 16 K-slabs
// of the block's X slice (contiguous 128 B-granule reads) into 32 KB LDS as
// bf16 in A-FRAGMENT order, then a barrier-free 16-slab K-loop with W depth-2
// register prefetch (survives the half-boundary barriers). 3 barriers total.
// Writes Q,K as bf16 [b, s, 64]; V transposed as bf16 [b, 64, s].
// ---------------------------------------------------------------------------
__global__ __launch_bounds__(256) void qkv_gemm(
    const float* __restrict__ X, const unsigned short* __restrict__ Wp,
    unsigned short* __restrict__ Qb, unsigned short* __restrict__ Kb,
    unsigned short* __restrict__ Vt) {
  __shared__ ushort8_t Af[2048];   // 32 KB: [(ksl*4+quad)*32 + row], ksl 0..15

  const int tid = threadIdx.x;
  const int lane = tid & 63;
  const int wave = tid >> 6;
  const int l15 = lane & 15;
  const int quad = lane >> 4;
  const int m0 = blockIdx.x * 32;
  const int nt0 = wave * 3;

  const int sr = tid >> 3;        // staging row 0..31
  const int sk = tid & 7;         // staging ks octet
  const float* xrow = X + (size_t)(m0 + sr) * DIN;

  // W depth-2 prefetch over global ks (registers persist across barriers)
  const ushort8_t* wp = reinterpret_cast<const ushort8_t*>(Wp) + nt0 * 2048 + lane;
  ushort8_t breg[2][3];
#pragma unroll
  for (int p = 0; p < 2; ++p)
#pragma unroll
    for (int nt = 0; nt < 3; ++nt) breg[p][nt] = wp[p * 64 + nt * 2048];

  f32x4 acc[2][3];
#pragma unroll
  for (int mt = 0; mt < 2; ++mt)
#pragma unroll
    for (int nt = 0; nt < 3; ++nt) acc[mt][nt] = (f32x4){0.f, 0.f, 0.f, 0.f};

  for (int half = 0; half < 2; ++half) {
    const int ksbase = half * 16;
    if (half) __syncthreads();   // all waves done reading Af half 0
    // ---- stage 16 slabs: contiguous reads, convert, A-frag-order LDS ----
#pragma unroll
    for (int p = 0; p < 2; ++p) {
      const int ksl = sk + p * 8;
      const float4* src =
          reinterpret_cast<const float4*>(xrow + (ksbase + ksl) * 32);
      float4 f[8];
#pragma unroll
      for (int i = 0; i < 8; ++i) f[i] = src[i];
#pragma unroll
      for (int q = 0; q < 4; ++q)
        Af[(ksl * 4 + q) * 32 + sr] =
            __builtin_bit_cast(ushort8_t, cvt8pair(f[q * 2], f[q * 2 + 1]));
    }
    __syncthreads();

    // ---- barrier-free 16-slab K loop ----
    for (int ksl = 0; ksl < 16; ++ksl) {
      const int ks = ksbase + ksl;
      const int p = ks & 1;
      bf16x8 af0 = __builtin_bit_cast(bf16x8, Af[(ksl * 4 + quad) * 32 + l15]);
      bf16x8 af1 = __builtin_bit_cast(bf16x8, Af[(ksl * 4 + quad) * 32 + 16 + l15]);
      bf16x8 b0 = __builtin_bit_cast(bf16x8, breg[p][0]);
      bf16x8 b1 = __builtin_bit_cast(bf16x8, breg[p][1]);
      bf16x8 b2 = __builtin_bit_cast(bf16x8, breg[p][2]);
      if (ks < 30) {
#pragma unroll
        for (int nt = 0; nt < 3; ++nt)
          breg[p][nt] = wp[(ks + 2) * 64 + nt * 2048];
      }
      acc[0][0] = __builtin_amdgcn_mfma_f32_16x16x32_bf16(af0, b0, acc[0][0], 0, 0, 0);
      acc[0][1] = __builtin_amdgcn_mfma_f32_16x16x32_bf16(af0, b1, acc[0][1], 0, 0, 0);
      acc[0][2] = __builtin_amdgcn_mfma_f32_16x16x32_bf16(af0, b2, acc[0][2], 0, 0, 0);
      acc[1][0] = __builtin_amdgcn_mfma_f32_16x16x32_bf16(af1, b0, acc[1][0], 0, 0, 0);
      acc[1][1] = __builtin_amdgcn_mfma_f32_16x16x32_bf16(af1, b1, acc[1][1], 0, 0, 0);
      acc[1][2] = __builtin_amdgcn_mfma_f32_16x16x32_bf16(af1, b2, acc[1][2], 0, 0, 0);
    }
  }

  // Epilogue. C/D layout: col = (nt0+nt)*16 + (lane&15), row = quad*4 + reg.
#pragma unroll
  for (int mt = 0; mt < 2; ++mt) {
    const int srow = m0 + mt * 16 + quad * 4;   // global row (b*2048+s) of reg 0
    const int b = srow >> 11;
    const int s = srow & 2047;
#pragma unroll
    for (int nt = 0; nt < 3; ++nt) {
      const f32x4 a = acc[mt][nt];
      const int n = (nt0 + nt) * 16 + l15;
      if (n < 64) {
#pragma unroll
        for (int r = 0; r < 4; ++r)
          Qb[(size_t)(srow + r) * 64 + n] = bfu(a[r]);
      } else if (n < 128) {
#pragma unroll
        for (int r = 0; r < 4; ++r)
          Kb[(size_t)(srow + r) * 64 + (n - 64)] = bfu(a[r]);
      } else {
        const int dv = n - 128;
        ushort4 t4;
        t4.x = bfu(a[0]); t4.y = bfu(a[1]);
        t4.z = bfu(a[2]); t4.w = bfu(a[3]);
        *reinterpret_cast<ushort4*>(Vt + (((size_t)(b * 64 + dv)) << 11) + s) = t4;
      }
    }
  }
}

// ---------------------------------------------------------------------------
// Kernel 2: causal flash attention main, max-free softmax, FULLY independent
// waves. Grid 1024 = 2-way k-split of 512 32-row q-blocks; slot = khalf*4 +
// wave handles k-tiles kt = slot, slot+8, ... (stride 8). No barriers, no
// in-block merge: each wave writes its partial O (row-major fp32) and l to
// workspace; kernel 3 sums the 8 slots. LDS = Pf only (16 KB) -> high
// co-residency. K prefetched one iteration ahead, V for the current tile
// issued before the exp/LDS phase. Longest-first q order; batch = g&7 keeps
// a batch's K/V on one XCD's L2.
// ---------------------------------------------------------------------------
__global__ __launch_bounds__(256) void flash_main(
    const unsigned short* __restrict__ Qb, const unsigned short* __restrict__ Kb,
    const unsigned short* __restrict__ Vt, float* __restrict__ Po,
    float* __restrict__ Pl) {
  __shared__ unsigned short Pf[4][2][2][512];   // 16 KB [wave][mt][c][lane*8+j]

  const int tid = threadIdx.x;
  const int lane = tid & 63;
  const int wave = tid >> 6;
  const int l15 = lane & 15;
  const int quad = lane >> 4;

  const int g = blockIdx.x;
  const int batch = g & 7;
  const int qb = 63 - ((g >> 3) & 63);  // 32-row q-block, longest-first
  const int khalf = g >> 9;             // 0 or 1
  const int q0 = qb * 32;
  const int n64 = (q0 + 95) >> 6;       // causal 64-wide k-tile count
  const int slot = khalf * 4 + wave;    // 0..7, also kt start (stride 8)
  const int qg = batch * 64 + qb;       // storage index

  // Q A-fragments for both m-tiles (row = lane&15, k = quad*8+j), d halves
  bf16x8 qf[2][2];
#pragma unroll
  for (int mt = 0; mt < 2; ++mt) {
    const ushort8_t* qp = reinterpret_cast<const ushort8_t*>(
        Qb + (size_t)(batch * SEQ + q0 + mt * 16 + l15) * 64);
    qf[mt][0] = __builtin_bit_cast(bf16x8, qp[quad]);
    qf[mt][1] = __builtin_bit_cast(bf16x8, qp[4 + quad]);
  }

  const ushort8_t* kbase = reinterpret_cast<const ushort8_t*>(
      Kb + (size_t)(batch * SEQ + l15) * 64);
  const unsigned short* vtb = Vt + ((size_t)(batch * 64) << 11);

  f32x4 o[2][4];
  float lacc[2][4];
#pragma unroll
  for (int mt = 0; mt < 2; ++mt)
#pragma unroll
    for (int i = 0; i < 4; ++i) {
      o[mt][i] = (f32x4){0.f, 0.f, 0.f, 0.f};
      lacc[mt][i] = 0.f;
    }

  // K fragment buffer, prefetched one iteration ahead
  ushort8_t kbuf[8];
  if (slot < n64) {
#pragma unroll
    for (int h = 0; h < 4; ++h) {
      const ushort8_t* kp = kbase + (size_t)(slot * 64 + h * 16) * 8;
      kbuf[h * 2] = kp[quad];
      kbuf[h * 2 + 1] = kp[4 + quad];
    }
  }

  for (int kt = slot; kt < n64; kt += 8) {
    const int k0 = kt * 64;
    // S = Q K^T (32 q-rows x 64 kj-cols) from prefetched kbuf
    f32x4 s[2][4];
#pragma unroll
    for (int h = 0; h < 4; ++h) {
      bf16x8 kf0 = __builtin_bit_cast(bf16x8, kbuf[h * 2]);
      bf16x8 kf1 = __builtin_bit_cast(bf16x8, kbuf[h * 2 + 1]);
#pragma unroll
      for (int mt = 0; mt < 2; ++mt) {
        f32x4 z = (f32x4){0.f, 0.f, 0.f, 0.f};
        z = __builtin_amdgcn_mfma_f32_16x16x32_bf16(qf[mt][0], kf0, z, 0, 0, 0);
        z = __builtin_amdgcn_mfma_f32_16x16x32_bf16(qf[mt][1], kf1, z, 0, 0, 0);
        s[mt][h] = z;
      }
    }
    // Prefetch K for tile kt+8 (kbuf consumed above; clamped in-range)
    {
      const int nk = (kt + 8 < n64) ? kt + 8 : n64 - 1;
#pragma unroll
      for (int h = 0; h < 4; ++h) {
        const ushort8_t* kp = kbase + (size_t)(nk * 64 + h * 16) * 8;
        kbuf[h * 2] = kp[quad];
        kbuf[h * 2 + 1] = kp[4 + quad];
      }
    }
    // Prefetch V for the CURRENT tile (consumed after the exp/LDS phase)
    ushort8_t vbuf[8];
#pragma unroll
    for (int c = 0; c < 2; ++c)
#pragma unroll
      for (int nt = 0; nt < 4; ++nt)
        vbuf[c * 4 + nt] = reinterpret_cast<const ushort8_t*>(
            vtb + (((size_t)(nt * 16 + l15)) << 11) + k0 + c * 32)[quad];
    // Causal mask — only the diagonal (last) k-tile crosses it.
    if (kt == n64 - 1) {
#pragma unroll
      for (int mt = 0; mt < 2; ++mt)
#pragma unroll
        for (int h = 0; h < 4; ++h) {
          const int col = k0 + h * 16 + l15;
#pragma unroll
          for (int r = 0; r < 4; ++r) {
            const int row = q0 + mt * 16 + quad * 4 + r;
            if (col > row) s[mt][h][r] = -INFINITY;
          }
        }
    }
    // p = exp(s); per-lane l partials; write P to LDS in bf16 A-frag order:
    // value (qrow = quad*4+r, kcol = h*16+l15) -> c = h>>1,
    // lane' = ((h&1)*2 + (l15>>3))*16 + (quad*4+r), j = l15&7
#pragma unroll
    for (int mt = 0; mt < 2; ++mt) {
#pragma unroll
      for (int h = 0; h < 4; ++h) {
        const int c = h >> 1;
        const int lp = ((h & 1) * 2 + (l15 >> 3)) * 16 + quad * 4;
        const int j = l15 & 7;
#pragma unroll
        for (int r = 0; r < 4; ++r) {
          const float pv = __expf(s[mt][h][r]);
          lacc[mt][r] += pv;
          Pf[wave][mt][c][(lp + r) * 8 + j] = bfu(pv);
        }
      }
    }
    // PV: O += P (32x64) * V (64x64) from prefetched vbuf
#pragma unroll
    for (int c = 0; c < 2; ++c) {
      bf16x8 pfm[2];
#pragma unroll
      for (int mt = 0; mt < 2; ++mt)
        pfm[mt] = __builtin_bit_cast(bf16x8,
            reinterpret_cast<const ushort8_t*>(&Pf[wave][mt][c][0])[lane]);
#pragma unroll
      for (int nt = 0; nt < 4; ++nt) {
        bf16x8 vf = __builtin_bit_cast(bf16x8, vbuf[c * 4 + nt]);
#pragma unroll
        for (int mt = 0; mt < 2; ++mt)
          o[mt][nt] = __builtin_amdgcn_mfma_f32_16x16x32_bf16(pfm[mt], vf, o[mt][nt], 0, 0, 0);
      }
    }
  }

  // l reduction across the 16 lanes of each quad-group
#pragma unroll
  for (int off = 1; off < 16; off <<= 1)
#pragma unroll
    for (int mt = 0; mt < 2; ++mt)
#pragma unroll
      for (int r = 0; r < 4; ++r)
        lacc[mt][r] += __shfl_xor(lacc[mt][r], off, 64);

  // Write this wave's partial (row-major, so the merge kernel coalesces).
  // C/D layout: value (row = mt*16 + quad*4 + r, col = nt*16 + l15).
  float* po = Po + (size_t)(qg * 8 + slot) * 2048;
#pragma unroll
  for (int mt = 0; mt < 2; ++mt)
#pragma unroll
    for (int nt = 0; nt < 4; ++nt)
#pragma unroll
      for (int r = 0; r < 4; ++r)
        po[(mt * 16 + quad * 4 + r) * 64 + nt * 16 + l15] = o[mt][nt][r];
  if (l15 == 0) {
    float* pl = Pl + (size_t)(qg * 8 + slot) * 32;
#pragma unroll
    for (int mt = 0; mt < 2; ++mt)
#pragma unroll
      for (int r = 0; r < 4; ++r)
        pl[mt * 16 + quad * 4 + r] = lacc[mt][r];
  }
}

// ---------------------------------------------------------------------------
// Kernel 3: merge the 8 k-slot partials per q-row and write Out.
// Block = 256 threads covers 4 output rows x 64 cols; fully coalesced.
// ---------------------------------------------------------------------------
__global__ __launch_bounds__(256) void flash_merge(
    const float* __restrict__ Po, const float* __restrict__ Pl,
    float* __restrict__ Out) {
  const int tid = threadIdx.x;
  const int col = tid & 63;
  const int rq = tid >> 6;
  const int brow = blockIdx.x * 4 + rq;   // global row 0..16383 (b*2048+s)
  const int s = brow & 2047;
  const int qg = (brow >> 11) * 64 + (s >> 5);
  const int row = s & 31;
  const float* po = Po + (size_t)(qg * 8) * 2048 + row * 64 + col;
  const float* pl = Pl + (size_t)(qg * 8) * 32 + row;
  float acc = 0.f, l = 0.f;
#pragma unroll
  for (int slot = 0; slot < 8; ++slot) {
    acc += po[(size_t)slot * 2048];
    l += pl[slot * 32];
  }
  Out[(size_t)brow * 64 + col] = acc / l;
}

// ---------------------------------------------------------------------------
extern "C" void kernel_launch(void* const* d_in, const int* in_sizes, int n_in,
                              void* d_out, int out_size, void* d_ws, size_t ws_size,
                              hipStream_t stream) {
  const float* X  = (const float*)d_in[0];
  const float* Wq = (const float*)d_in[1];
  const float* Wk = (const float*)d_in[2];
  const float* Wv = (const float*)d_in[3];
  float* Out = (float*)d_out;

  char* ws = (char*)d_ws;
  // Workspace layout (all overwritten every launch):
  //   Wp : 384 KB   Qb/Kb/Vt : 2 MB each   Po : 32 MB   Pl : 512 KB
  unsigned short* Wp = (unsigned short*)ws;
  unsigned short* Qb = (unsigned short*)(ws + (400 << 10));
  unsigned short* Kb = (unsigned short*)(ws + (400 << 10) + (2 << 20));
  unsigned short* Vt = (unsigned short*)(ws + (400 << 10) + (4 << 20));
  float* Po = (float*)(ws + (8 << 20));
  float* Pl = (float*)(ws + (44 << 20));

  pack_w<<<96, 256, 0, stream>>>(Wq, Wk, Wv, Wp);
  qkv_gemm<<<512, 256, 0, stream>>>(X, Wp, Qb, Kb, Vt);
  flash_main<<<1024, 256, 0, stream>>>(Qb, Kb, Vt, Po, Pl);
  flash_merge<<<4096, 256, 0, stream>>>(Po, Pl, Out);
}